// Round 14
// baseline (4875.125 us; speedup 1.0000x reference)
//
#include <hip/hip_runtime.h>
#include <hip/hip_bf16.h>
#include <math.h>

// Problem constants: B=4, DIM=512, H=W=64 -> L=4096 tokens/batch, NH=8, HD=64, CS=16, NC=256
#define L_TOK 4096
#define DIMC  512

static __device__ __forceinline__ float4 f4fma(float a, const float4 b, const float4 c) {
    return make_float4(fmaf(a, b.x, c.x), fmaf(a, b.y, c.y), fmaf(a, b.z, c.z), fmaf(a, b.w, c.w));
}

// ---------------- RoPE cos/sin table (mirrors JAX fp32 ops) ----------------
__global__ __launch_bounds__(256) void rope_table_kernel(float* __restrict__ ctab, float* __restrict__ stab) {
    int idx = blockIdx.x * 256 + threadIdx.x;
    if (idx >= L_TOK * 32) return;
    int t = idx >> 5, m = idx & 31;
    float inv = 1.0f / powf(10000.0f, (float)(2 * m) * (1.0f / 64.0f));
    float fr = (float)t * inv;           // fp32 product, like JAX
    ctab[idx] = cosf(fr);
    stab[idx] = sinf(fr);
}

// ---------------- Transpose + LayerNorm (eps 1e-5): x(B,512,4096) -> xn(B,4096,512) ----------------
__global__ __launch_bounds__(256) void ln_in_kernel(const float* __restrict__ x,
                                                    const float* __restrict__ w,
                                                    const float* __restrict__ bia,
                                                    float* __restrict__ xn) {
    __shared__ float tile[16][516];
    __shared__ float redA[4][16], redB[4][16];
    __shared__ float mu_s[16], rs_s[16];
    int blk = blockIdx.x;                // B * 256 tiles
    int b = blk >> 8;
    int t0 = (blk & 255) << 4;
    int tid = threadIdx.x;
    int tt = tid & 15, cg = tid >> 4;
    int wid = tid >> 6;
    const float* xp = x + (size_t)b * DIMC * L_TOK + t0 + tt;
    float sum = 0.0f, sq = 0.0f;
#pragma unroll
    for (int i = 0; i < 32; i++) {
        int c = cg + (i << 4);
        float v = xp[(size_t)c * L_TOK];
        tile[tt][c] = v;
        sum += v; sq += v * v;
    }
    sum += __shfl_xor(sum, 16); sum += __shfl_xor(sum, 32);
    sq  += __shfl_xor(sq, 16);  sq  += __shfl_xor(sq, 32);
    if ((tid & 63) < 16) { redA[wid][tt] = sum; redB[wid][tt] = sq; }
    __syncthreads();
    if (tid < 16) {
        float s = redA[0][tid] + redA[1][tid] + redA[2][tid] + redA[3][tid];
        float q = redB[0][tid] + redB[1][tid] + redB[2][tid] + redB[3][tid];
        float mu = s * (1.0f / 512.0f);
        mu_s[tid] = mu;
        rs_s[tid] = rsqrtf(q * (1.0f / 512.0f) - mu * mu + 1e-5f);
    }
    __syncthreads();
    int half = tid >> 7;
    int cc = (tid & 127) << 2;
    float4 wv = *(const float4*)&w[cc];
    float4 bv = *(const float4*)&bia[cc];
    float* xnp = xn + ((size_t)b * L_TOK + t0) * DIMC;
#pragma unroll
    for (int i = 0; i < 8; i++) {
        int rr = half + (i << 1);
        float mu = mu_s[rr], rs = rs_s[rr];
        float4 v = *(float4*)&tile[rr][cc];
        float4 o;
        o.x = fmaf((v.x - mu) * rs, wv.x, bv.x);
        o.y = fmaf((v.y - mu) * rs, wv.y, bv.y);
        o.z = fmaf((v.z - mu) * rs, wv.z, bv.z);
        o.w = fmaf((v.w - mu) * rs, wv.w, bv.w);
        *(float4*)&xnp[(size_t)rr * DIMC + cc] = o;
    }
}

// ---------------- lr_eta: sigmoid(xn . lr_w[h] + lr_b[h]) / 64, layout (B,NH,L) ----------------
__global__ __launch_bounds__(256) void lr_kernel(const float* __restrict__ xn,
                                                 const float* __restrict__ lrw,
                                                 const float* __restrict__ lrb,
                                                 float* __restrict__ lre) {
    int tid = threadIdx.x;
    int lane = tid & 63, wid = tid >> 6;
    int tok = blockIdx.x * 4 + wid;      // < 16384
    const float* xp = xn + (size_t)tok * DIMC + lane * 8;
    float4 a0 = *(const float4*)xp;
    float4 a1 = *(const float4*)(xp + 4);
    int bb = tok >> 12, t = tok & 4095;
#pragma unroll
    for (int h = 0; h < 8; h++) {
        const float* wp = lrw + h * DIMC + lane * 8;
        float4 w0 = *(const float4*)wp;
        float4 w1 = *(const float4*)(wp + 4);
        float s = a0.x * w0.x + a0.y * w0.y + a0.z * w0.z + a0.w * w0.w
                + a1.x * w1.x + a1.y * w1.y + a1.z * w1.z + a1.w * w1.w;
        s += __shfl_xor(s, 1); s += __shfl_xor(s, 2); s += __shfl_xor(s, 4);
        s += __shfl_xor(s, 8); s += __shfl_xor(s, 16); s += __shfl_xor(s, 32);
        if (lane == 0) {
            float v = s + lrb[h];
            lre[(size_t)(bb * 8 + h) * L_TOK + t] = (1.0f / 64.0f) / (1.0f + expf(-v));
        }
    }
}

// ---------------- QKV GEMM: 128x64 tile, y = xn @ w.T, scatter to (B,NH,L,HD) ----------------
__global__ __launch_bounds__(256) void qkv_gemm_kernel(const float* __restrict__ A,
                                                       const float* __restrict__ qw,
                                                       const float* __restrict__ kw,
                                                       const float* __restrict__ vw,
                                                       float* __restrict__ XQ,
                                                       float* __restrict__ XK,
                                                       float* __restrict__ XV) {
    __shared__ float As[16][136];   // A-tile transposed: [k][row], stride 136
    __shared__ float Bs[16][68];
    int tid = threadIdx.x;
    int mt = blockIdx.x, nt = blockIdx.y;            // 128 x 24
    const float* wsel = (nt < 8) ? qw : (nt < 16) ? kw : vw;
    int h = nt & 7;
    int arow = tid >> 1, ak = (tid & 1) << 3;        // A: 128 rows x 16 k
    int brow = tid >> 2, bk = (tid & 3) << 2;        // B: 64 rows x 16 k
    int tm8 = (tid >> 4) << 3, tn = tid & 15;
    float acc[8][4] = {};
    const float* ap = A + (size_t)(mt * 128 + arow) * DIMC + ak;
    const float* bp = wsel + (size_t)(h * 64 + brow) * DIMC + bk;
    for (int k0 = 0; k0 < DIMC; k0 += 16) {
        float4 a0 = *(const float4*)(ap + k0);
        float4 a1 = *(const float4*)(ap + k0 + 4);
        float4 bv = *(const float4*)(bp + k0);
        As[ak + 0][arow] = a0.x; As[ak + 1][arow] = a0.y; As[ak + 2][arow] = a0.z; As[ak + 3][arow] = a0.w;
        As[ak + 4][arow] = a1.x; As[ak + 5][arow] = a1.y; As[ak + 6][arow] = a1.z; As[ak + 7][arow] = a1.w;
        Bs[bk + 0][brow] = bv.x; Bs[bk + 1][brow] = bv.y; Bs[bk + 2][brow] = bv.z; Bs[bk + 3][brow] = bv.w;
        __syncthreads();
#pragma unroll
        for (int kk = 0; kk < 16; kk++) {
            float4 va0 = *(const float4*)&As[kk][tm8];
            float4 va1 = *(const float4*)&As[kk][tm8 + 4];
            float4 vb  = *(const float4*)&Bs[kk][tn << 2];
            float aa[8] = {va0.x, va0.y, va0.z, va0.w, va1.x, va1.y, va1.z, va1.w};
            float bb[4] = {vb.x, vb.y, vb.z, vb.w};
#pragma unroll
            for (int i = 0; i < 8; i++)
#pragma unroll
                for (int j = 0; j < 4; j++)
                    acc[i][j] = fmaf(aa[i], bb[j], acc[i][j]);
        }
        __syncthreads();
    }
    int m0 = mt * 128 + tm8;                     // tile never straddles a batch (4096/128=32)
    int bb2 = m0 >> 12, t = m0 & 4095;
    float* dst = (nt < 8) ? XQ : (nt < 16) ? XK : XV;
    dst += ((size_t)(bb2 * 8 + h) * L_TOK + t) * 64 + (tn << 2);
#pragma unroll
    for (int i = 0; i < 8; i++)
        *(float4*)(dst + (size_t)i * 64) = make_float4(acc[i][0], acc[i][1], acc[i][2], acc[i][3]);
}

// ---------------- RoPE in-place on XQ and XK ----------------
__global__ __launch_bounds__(256) void rope_kernel(float* __restrict__ XQ, float* __restrict__ XK,
                                                   const float* __restrict__ ctab,
                                                   const float* __restrict__ stab) {
    int idx = blockIdx.x * 256 + threadIdx.x;   // 2 * 32 * 4096 * 32
    int d = idx & 31;
    int t = (idx >> 5) & 4095;
    int bh = (idx >> 17) & 31;
    int tensor = idx >> 22;
    float* p = (tensor ? XK : XQ) + ((size_t)bh * L_TOK + t) * 64;
    float c = ctab[(t << 5) + d], s = stab[(t << 5) + d];
    float x1 = p[d], x2 = p[d + 32];
    p[d] = x1 * c - x2 * s;
    p[d + 32] = x2 * c + x1 * s;
}

// ---------------- TTT scan: 16 blocks x 2 chains (b,h), 256 chunks each ----------------
// Round-14: the functionally-verified 2-chain kernel (rounds 10/11, passed twice)
// with the CORRECT register-budget knob: amdgpu_waves_per_eu(2,2). max=2 waves/EU
// licenses 512/2 = 256 VGPR for this 512-thread workgroup (body needs ~204).
// Rounds 10/11 failed because the default heuristic targeted 4 waves/EU (128 VGPR)
// and __launch_bounds__' 2nd arg can only LOWER the cap, not raise it.
__global__ __launch_bounds__(512) __attribute__((amdgpu_waves_per_eu(2, 2)))
void scan_kernel(const float* __restrict__ XQ,
                 const float* __restrict__ XK,
                 const float* __restrict__ XV,
                 const float* __restrict__ lre,
                 const float* __restrict__ tok_delta,
                 const float* __restrict__ W1i,
                 const float* __restrict__ b1i,
                 const float* __restrict__ tw,
                 const float* __restrict__ tb,
                 float* __restrict__ attn_out) {
    __shared__ float W1[2][64][64];
    __shared__ float b1v[2][64];
    __shared__ float xqs[2][2][16][68], xks[2][2][16][68], xvs[2][2][16][68];
    __shared__ float grads[2][16][68];
    __shared__ float etas[2][2][16];
    __shared__ float coefC[2][16][17];
    __shared__ float sj[2][16];
    int tid = threadIdx.x;
    int ch = tid >> 8;                    // chain within block (0/1), wave-aligned
    int t  = tid & 255;
    int r = t >> 4, dq = t & 15, d0 = dq << 2;
    int bh = blockIdx.x * 2 + ch, h = bh & 7, b = bh >> 3;
#pragma unroll
    for (int i = 0; i < 4; i++) {
        int c = r + (i << 4);
        *(float4*)&W1[ch][c][d0] = *(const float4*)&W1i[(size_t)h * 4096 + c * 64 + d0];
    }
    if (r == 0) *(float4*)&b1v[ch][d0] = *(const float4*)&b1i[h * 64 + d0];
    float4 gw = *(const float4*)&tw[h * 64 + d0];
    float4 bw = *(const float4*)&tb[h * 64 + d0];
    float tok_r = fmaxf(1.0f / (float)(r + 1) + tok_delta[r], 0.0f);
    float tok15 = fmaxf(1.0f / 16.0f + tok_delta[15], 0.0f);
    const size_t base = (size_t)bh * L_TOK * 64;
    {   // prologue: chunk 0
        size_t off = base + (size_t)r * 64 + d0;
        *(float4*)&xqs[ch][0][r][d0] = *(const float4*)(XQ + off);
        *(float4*)&xks[ch][0][r][d0] = *(const float4*)(XK + off);
        *(float4*)&xvs[ch][0][r][d0] = *(const float4*)(XV + off);
        if (t < 16) etas[ch][0][t] = lre[(size_t)bh * L_TOK + t];
    }
    __syncthreads();
    int cur = 0;
    for (int n = 0; n < 256; n++) {
        // prefetch next chunk into registers (overlaps compute)
        int np = (n < 255) ? n + 1 : 255;
        size_t poff = base + (size_t)np * 1024 + (size_t)r * 64 + d0;
        float4 pfq = *(const float4*)(XQ + poff);
        float4 pfk = *(const float4*)(XK + poff);
        float4 pfv = *(const float4*)(XV + poff);
        float pfe = 0.0f;
        if (t < 16) pfe = lre[(size_t)bh * L_TOK + np * 16 + t];

        // ---- Phase A: z = b1 + xk@W1 ; z2 = b1 + xq@W1 ; att = xq[r].xk[dq]
        float4 b1reg = *(float4*)&b1v[ch][d0];
        float4 z  = b1reg;
        float4 z2 = b1reg;
        float att = 0.0f;
#pragma unroll
        for (int c4 = 0; c4 < 16; c4++) {
            int c = c4 << 2;
            float4 xkr = *(float4*)&xks[ch][cur][r][c];
            float4 xqr = *(float4*)&xqs[ch][cur][r][c];
            float4 xkq = *(float4*)&xks[ch][cur][dq][c];
            float4 w0 = *(float4*)&W1[ch][c + 0][d0];
            float4 w1 = *(float4*)&W1[ch][c + 1][d0];
            float4 w2 = *(float4*)&W1[ch][c + 2][d0];
            float4 w3 = *(float4*)&W1[ch][c + 3][d0];
            att += xqr.x * xkq.x + xqr.y * xkq.y + xqr.z * xkq.z + xqr.w * xkq.w;
            z  = f4fma(xkr.x, w0, z);  z  = f4fma(xkr.y, w1, z);
            z  = f4fma(xkr.z, w2, z);  z  = f4fma(xkr.w, w3, z);
            z2 = f4fma(xqr.x, w0, z2); z2 = f4fma(xqr.y, w1, z2);
            z2 = f4fma(xqr.z, w2, z2); z2 = f4fma(xqr.w, w3, z2);
        }
        // ---- LN-L2 backward on z -> grad
        float s = z.x + z.y + z.z + z.w;
        s += __shfl_xor(s, 1); s += __shfl_xor(s, 2); s += __shfl_xor(s, 4); s += __shfl_xor(s, 8);
        float mu = s * (1.0f / 64.0f);
        float4 dz = make_float4(z.x - mu, z.y - mu, z.z - mu, z.w - mu);
        float q = dz.x * dz.x + dz.y * dz.y + dz.z * dz.z + dz.w * dz.w;
        q += __shfl_xor(q, 1); q += __shfl_xor(q, 2); q += __shfl_xor(q, 4); q += __shfl_xor(q, 8);
        float rstd = rsqrtf(q * (1.0f / 64.0f) + 1e-6f);
        float4 xh = make_float4(dz.x * rstd, dz.y * rstd, dz.z * rstd, dz.w * rstd);
        float4 xvv = *(float4*)&xvs[ch][cur][r][d0];
        float4 xkk = *(float4*)&xks[ch][cur][r][d0];
        float4 gxh;
        gxh.x = (fmaf(gw.x, xh.x, bw.x) - (xvv.x - xkk.x)) * gw.x;
        gxh.y = (fmaf(gw.y, xh.y, bw.y) - (xvv.y - xkk.y)) * gw.y;
        gxh.z = (fmaf(gw.z, xh.z, bw.z) - (xvv.z - xkk.z)) * gw.z;
        gxh.w = (fmaf(gw.w, xh.w, bw.w) - (xvv.w - xkk.w)) * gw.w;
        float s1 = gxh.x + gxh.y + gxh.z + gxh.w;
        s1 += __shfl_xor(s1, 1); s1 += __shfl_xor(s1, 2); s1 += __shfl_xor(s1, 4); s1 += __shfl_xor(s1, 8);
        float s2 = gxh.x * xh.x + gxh.y * xh.y + gxh.z * xh.z + gxh.w * xh.w;
        s2 += __shfl_xor(s2, 1); s2 += __shfl_xor(s2, 2); s2 += __shfl_xor(s2, 4); s2 += __shfl_xor(s2, 8);
        float cgr = rstd * (1.0f / 64.0f);
        float4 grad;
        grad.x = (64.0f * gxh.x - s1 - xh.x * s2) * cgr;
        grad.y = (64.0f * gxh.y - s1 - xh.y * s2) * cgr;
        grad.z = (64.0f * gxh.z - s1 - xh.z * s2) * cgr;
        grad.w = (64.0f * gxh.w - s1 - xh.w * s2) * cgr;
        *(float4*)&grads[ch][r][d0] = grad;
        float ceta = etas[ch][cur][dq];
        coefC[ch][r][dq] = (dq <= r) ? tok_r * ceta * (1.0f + att) : 0.0f;
        if (r == 15) sj[ch][dq] = tok15 * ceta;
        __syncthreads();   // sync1: grads/coefC/sj ready; all W1/b1 reads done

        // ---- Phase B: z2 -= C@grad ; W1/b1 update accumulators (rows 4r..4r+3)
        int r4 = r << 2;
        float4 acc0 = make_float4(0, 0, 0, 0), acc1 = acc0, acc2 = acc0, acc3 = acc0, accb = acc0;
#pragma unroll
        for (int j = 0; j < 16; j++) {
            float4 gj = *(float4*)&grads[ch][j][d0];
            float cj = coefC[ch][r][j];
            float sjj = sj[ch][j];
            float4 xk4 = *(float4*)&xks[ch][cur][j][r4];
            z2 = f4fma(-cj, gj, z2);
            acc0 = f4fma(sjj * xk4.x, gj, acc0);
            acc1 = f4fma(sjj * xk4.y, gj, acc1);
            acc2 = f4fma(sjj * xk4.z, gj, acc2);
            acc3 = f4fma(sjj * xk4.w, gj, acc3);
            accb = f4fma(sjj, gj, accb);
        }
        // ---- LN forward on z2 -> out = xq + LN(z2)
        float so = z2.x + z2.y + z2.z + z2.w;
        so += __shfl_xor(so, 1); so += __shfl_xor(so, 2); so += __shfl_xor(so, 4); so += __shfl_xor(so, 8);
        float mu2 = so * (1.0f / 64.0f);
        float4 dz2 = make_float4(z2.x - mu2, z2.y - mu2, z2.z - mu2, z2.w - mu2);
        float q2 = dz2.x * dz2.x + dz2.y * dz2.y + dz2.z * dz2.z + dz2.w * dz2.w;
        q2 += __shfl_xor(q2, 1); q2 += __shfl_xor(q2, 2); q2 += __shfl_xor(q2, 4); q2 += __shfl_xor(q2, 8);
        float rstd2 = rsqrtf(q2 * (1.0f / 64.0f) + 1e-6f);
        float4 xq4 = *(float4*)&xqs[ch][cur][r][d0];
        float4 o;
        o.x = fmaf(dz2.x * rstd2, gw.x, bw.x) + xq4.x;
        o.y = fmaf(dz2.y * rstd2, gw.y, bw.y) + xq4.y;
        o.z = fmaf(dz2.z * rstd2, gw.z, bw.z) + xq4.z;
        o.w = fmaf(dz2.w * rstd2, gw.w, bw.w) + xq4.w;
        *(float4*)(attn_out + ((size_t)b * L_TOK + (size_t)n * 16 + r) * DIMC + h * 64 + d0) = o;

        // ---- W1 RMW (in-place, rows 4r..4r+3): no reader until after sync2
        {
            float4 w0 = *(float4*)&W1[ch][r4 + 0][d0];
            *(float4*)&W1[ch][r4 + 0][d0] = make_float4(w0.x - acc0.x, w0.y - acc0.y, w0.z - acc0.z, w0.w - acc0.w);
            float4 w1 = *(float4*)&W1[ch][r4 + 1][d0];
            *(float4*)&W1[ch][r4 + 1][d0] = make_float4(w1.x - acc1.x, w1.y - acc1.y, w1.z - acc1.z, w1.w - acc1.w);
            float4 w2 = *(float4*)&W1[ch][r4 + 2][d0];
            *(float4*)&W1[ch][r4 + 2][d0] = make_float4(w2.x - acc2.x, w2.y - acc2.y, w2.z - acc2.z, w2.w - acc2.w);
            float4 w3 = *(float4*)&W1[ch][r4 + 3][d0];
            *(float4*)&W1[ch][r4 + 3][d0] = make_float4(w3.x - acc3.x, w3.y - acc3.y, w3.z - acc3.z, w3.w - acc3.w);
        }
        if (r == 0)
            *(float4*)&b1v[ch][d0] = make_float4(b1reg.x - accb.x, b1reg.y - accb.y, b1reg.z - accb.z, b1reg.w - accb.w);

        // ---- stage prefetched chunk into the other buffer
        int nxt = cur ^ 1;
        *(float4*)&xqs[ch][nxt][r][d0] = pfq;
        *(float4*)&xks[ch][nxt][r][d0] = pfk;
        *(float4*)&xvs[ch][nxt][r][d0] = pfv;
        if (t < 16) etas[ch][nxt][t] = pfe;
        __syncthreads();   // sync2: updated W1/b1 + staged inputs visible
        cur ^= 1;
    }
}

// ---------------- Post-LN (eps 1e-6) in-place on attn (B*L, 512) ----------------
__global__ __launch_bounds__(256) void post_ln_kernel(float* __restrict__ at,
                                                      const float* __restrict__ w,
                                                      const float* __restrict__ b) {
    __shared__ float redA[4], redB[4];
    int row = blockIdx.x, tid = threadIdx.x;
    float* p = at + (size_t)row * DIMC;
    float v0 = p[tid], v1 = p[tid + 256];
    float s = v0 + v1, q = v0 * v0 + v1 * v1;
    s += __shfl_xor(s, 1); s += __shfl_xor(s, 2); s += __shfl_xor(s, 4);
    s += __shfl_xor(s, 8); s += __shfl_xor(s, 16); s += __shfl_xor(s, 32);
    q += __shfl_xor(q, 1); q += __shfl_xor(q, 2); q += __shfl_xor(q, 4);
    q += __shfl_xor(q, 8); q += __shfl_xor(q, 16); q += __shfl_xor(q, 32);
    if ((tid & 63) == 0) { redA[tid >> 6] = s; redB[tid >> 6] = q; }
    __syncthreads();
    s = redA[0] + redA[1] + redA[2] + redA[3];
    q = redB[0] + redB[1] + redB[2] + redB[3];
    float mu = s * (1.0f / 512.0f);
    float rs = rsqrtf(q * (1.0f / 512.0f) - mu * mu + 1e-6f);
    p[tid]       = fmaf((v0 - mu) * rs, w[tid],       b[tid]);
    p[tid + 256] = fmaf((v1 - mu) * rs, w[tid + 256], b[tid + 256]);
}

// ---------------- Output GEMM: 128x64 tile, y = ln_out @ o_w.T, store transposed ----------------
__global__ __launch_bounds__(256) void out_gemm_kernel(const float* __restrict__ A,
                                                       const float* __restrict__ ow,
                                                       float* __restrict__ out) {
    __shared__ float As[16][136];
    __shared__ float Bs[16][68];
    int tid = threadIdx.x;
    int mt = blockIdx.x, nt = blockIdx.y;   // 128 x 8
    int arow = tid >> 1, ak = (tid & 1) << 3;
    int brow = tid >> 2, bk = (tid & 3) << 2;
    int tm8 = (tid >> 4) << 3, tn = tid & 15;
    float acc[8][4] = {};
    const float* ap = A + (size_t)(mt * 128 + arow) * DIMC + ak;
    const float* bp = ow + (size_t)(nt * 64 + brow) * DIMC + bk;
    for (int k0 = 0; k0 < DIMC; k0 += 16) {
        float4 a0 = *(const float4*)(ap + k0);
        float4 a1 = *(const float4*)(ap + k0 + 4);
        float4 bv = *(const float4*)(bp + k0);
        As[ak + 0][arow] = a0.x; As[ak + 1][arow] = a0.y; As[ak + 2][arow] = a0.z; As[ak + 3][arow] = a0.w;
        As[ak + 4][arow] = a1.x; As[ak + 5][arow] = a1.y; As[ak + 6][arow] = a1.z; As[ak + 7][arow] = a1.w;
        Bs[bk + 0][brow] = bv.x; Bs[bk + 1][brow] = bv.y; Bs[bk + 2][brow] = bv.z; Bs[bk + 3][brow] = bv.w;
        __syncthreads();
#pragma unroll
        for (int kk = 0; kk < 16; kk++) {
            float4 va0 = *(const float4*)&As[kk][tm8];
            float4 va1 = *(const float4*)&As[kk][tm8 + 4];
            float4 vb  = *(const float4*)&Bs[kk][tn << 2];
            float aa[8] = {va0.x, va0.y, va0.z, va0.w, va1.x, va1.y, va1.z, va1.w};
            float bb[4] = {vb.x, vb.y, vb.z, vb.w};
#pragma unroll
            for (int i = 0; i < 8; i++)
#pragma unroll
                for (int j = 0; j < 4; j++)
                    acc[i][j] = fmaf(aa[i], bb[j], acc[i][j]);
        }
        __syncthreads();
    }
    int m0 = mt * 128 + tm8;                 // tile never straddles a batch
    int bb2 = m0 >> 12, t = m0 & 4095;
    int n0 = nt * 64 + (tn << 2);
#pragma unroll
    for (int j = 0; j < 4; j++) {
        float* op = out + ((size_t)(bb2 * DIMC) + n0 + j) * L_TOK + t;
        *(float4*)op       = make_float4(acc[0][j], acc[1][j], acc[2][j], acc[3][j]);
        *(float4*)(op + 4) = make_float4(acc[4][j], acc[5][j], acc[6][j], acc[7][j]);
    }
}

// ---------------- launch ----------------
extern "C" void kernel_launch(void* const* d_in, const int* in_sizes, int n_in,
                              void* d_out, int out_size, void* d_ws, size_t ws_size,
                              hipStream_t stream) {
    (void)in_sizes; (void)n_in; (void)out_size; (void)ws_size;
    const float* x       = (const float*)d_in[0];
    const float* ln_w    = (const float*)d_in[1];
    const float* ln_b    = (const float*)d_in[2];
    const float* q_w     = (const float*)d_in[3];
    const float* k_w     = (const float*)d_in[4];
    const float* v_w     = (const float*)d_in[5];
    const float* o_w     = (const float*)d_in[6];
    const float* W1      = (const float*)d_in[7];
    const float* b1      = (const float*)d_in[8];
    const float* ttt_w   = (const float*)d_in[9];
    const float* ttt_b   = (const float*)d_in[10];
    const float* lr_w    = (const float*)d_in[11];
    const float* lr_b    = (const float*)d_in[12];
    const float* tok_d   = (const float*)d_in[13];
    const float* post_w  = (const float*)d_in[14];
    const float* post_b  = (const float*)d_in[15];

    float* ws = (float*)d_ws;
    const size_t NTD = (size_t)4 * L_TOK * DIMC;   // 8388608 floats = 32 MB
    // Workspace layout (~102 MB): xn | XQ | XK | lre | ctab | stab.
    // XV lives in d_out; it is fully consumed by scan_kernel before
    // out_gemm_kernel overwrites d_out with the final result.
    float* xn   = ws;
    float* XQb  = ws + NTD;
    float* XKb  = ws + 2 * NTD;
    float* XVb  = (float*)d_out;
    float* lre  = ws + 3 * NTD;
    float* ctab = lre + 131072;
    float* stab = ctab + 131072;
    float* attn = xn;

    rope_table_kernel<<<512, 256, 0, stream>>>(ctab, stab);
    ln_in_kernel<<<1024, 256, 0, stream>>>(x, ln_w, ln_b, xn);
    lr_kernel<<<4096, 256, 0, stream>>>(xn, lr_w, lr_b, lre);
    {
        dim3 g(128, 24);
        qkv_gemm_kernel<<<g, 256, 0, stream>>>(xn, q_w, k_w, v_w, XQb, XKb, XVb);
    }
    rope_kernel<<<32768, 256, 0, stream>>>(XQb, XKb, ctab, stab);
    scan_kernel<<<16, 512, 0, stream>>>(XQb, XKb, XVb, lre, tok_d, W1, b1, ttt_w, ttt_b, attn);
    post_ln_kernel<<<16384, 256, 0, stream>>>(attn, post_w, post_b);
    {
        dim3 g(128, 8);
        out_gemm_kernel<<<g, 256, 0, stream>>>(attn, o_w, (float*)d_out);
    }
}

// Round 15
// 1581.570 us; speedup vs baseline: 3.0825x; 3.0825x over previous
//
#include <hip/hip_runtime.h>
#include <hip/hip_bf16.h>
#include <math.h>

// Problem constants: B=4, DIM=512, H=W=64 -> L=4096 tokens/batch, NH=8, HD=64, CS=16, NC=256
#define L_TOK 4096
#define DIMC  512

static __device__ __forceinline__ float4 f4fma(float a, const float4 b, const float4 c) {
    return make_float4(fmaf(a, b.x, c.x), fmaf(a, b.y, c.y), fmaf(a, b.z, c.z), fmaf(a, b.w, c.w));
}

// ---------------- RoPE cos/sin table (mirrors JAX fp32 ops) ----------------
__global__ __launch_bounds__(256) void rope_table_kernel(float* __restrict__ ctab, float* __restrict__ stab) {
    int idx = blockIdx.x * 256 + threadIdx.x;
    if (idx >= L_TOK * 32) return;
    int t = idx >> 5, m = idx & 31;
    float inv = 1.0f / powf(10000.0f, (float)(2 * m) * (1.0f / 64.0f));
    float fr = (float)t * inv;           // fp32 product, like JAX
    ctab[idx] = cosf(fr);
    stab[idx] = sinf(fr);
}

// ---------------- Transpose + LayerNorm (eps 1e-5): x(B,512,4096) -> xn(B,4096,512) ----------------
__global__ __launch_bounds__(256) void ln_in_kernel(const float* __restrict__ x,
                                                    const float* __restrict__ w,
                                                    const float* __restrict__ bia,
                                                    float* __restrict__ xn) {
    __shared__ float tile[16][516];
    __shared__ float redA[4][16], redB[4][16];
    __shared__ float mu_s[16], rs_s[16];
    int blk = blockIdx.x;                // B * 256 tiles
    int b = blk >> 8;
    int t0 = (blk & 255) << 4;
    int tid = threadIdx.x;
    int tt = tid & 15, cg = tid >> 4;
    int wid = tid >> 6;
    const float* xp = x + (size_t)b * DIMC * L_TOK + t0 + tt;
    float sum = 0.0f, sq = 0.0f;
#pragma unroll
    for (int i = 0; i < 32; i++) {
        int c = cg + (i << 4);
        float v = xp[(size_t)c * L_TOK];
        tile[tt][c] = v;
        sum += v; sq += v * v;
    }
    sum += __shfl_xor(sum, 16); sum += __shfl_xor(sum, 32);
    sq  += __shfl_xor(sq, 16);  sq  += __shfl_xor(sq, 32);
    if ((tid & 63) < 16) { redA[wid][tt] = sum; redB[wid][tt] = sq; }
    __syncthreads();
    if (tid < 16) {
        float s = redA[0][tid] + redA[1][tid] + redA[2][tid] + redA[3][tid];
        float q = redB[0][tid] + redB[1][tid] + redB[2][tid] + redB[3][tid];
        float mu = s * (1.0f / 512.0f);
        mu_s[tid] = mu;
        rs_s[tid] = rsqrtf(q * (1.0f / 512.0f) - mu * mu + 1e-5f);
    }
    __syncthreads();
    int half = tid >> 7;
    int cc = (tid & 127) << 2;
    float4 wv = *(const float4*)&w[cc];
    float4 bv = *(const float4*)&bia[cc];
    float* xnp = xn + ((size_t)b * L_TOK + t0) * DIMC;
#pragma unroll
    for (int i = 0; i < 8; i++) {
        int rr = half + (i << 1);
        float mu = mu_s[rr], rs = rs_s[rr];
        float4 v = *(float4*)&tile[rr][cc];
        float4 o;
        o.x = fmaf((v.x - mu) * rs, wv.x, bv.x);
        o.y = fmaf((v.y - mu) * rs, wv.y, bv.y);
        o.z = fmaf((v.z - mu) * rs, wv.z, bv.z);
        o.w = fmaf((v.w - mu) * rs, wv.w, bv.w);
        *(float4*)&xnp[(size_t)rr * DIMC + cc] = o;
    }
}

// ---------------- lr_eta: sigmoid(xn . lr_w[h] + lr_b[h]) / 64, layout (B,NH,L) ----------------
__global__ __launch_bounds__(256) void lr_kernel(const float* __restrict__ xn,
                                                 const float* __restrict__ lrw,
                                                 const float* __restrict__ lrb,
                                                 float* __restrict__ lre) {
    int tid = threadIdx.x;
    int lane = tid & 63, wid = tid >> 6;
    int tok = blockIdx.x * 4 + wid;      // < 16384
    const float* xp = xn + (size_t)tok * DIMC + lane * 8;
    float4 a0 = *(const float4*)xp;
    float4 a1 = *(const float4*)(xp + 4);
    int bb = tok >> 12, t = tok & 4095;
#pragma unroll
    for (int h = 0; h < 8; h++) {
        const float* wp = lrw + h * DIMC + lane * 8;
        float4 w0 = *(const float4*)wp;
        float4 w1 = *(const float4*)(wp + 4);
        float s = a0.x * w0.x + a0.y * w0.y + a0.z * w0.z + a0.w * w0.w
                + a1.x * w1.x + a1.y * w1.y + a1.z * w1.z + a1.w * w1.w;
        s += __shfl_xor(s, 1); s += __shfl_xor(s, 2); s += __shfl_xor(s, 4);
        s += __shfl_xor(s, 8); s += __shfl_xor(s, 16); s += __shfl_xor(s, 32);
        if (lane == 0) {
            float v = s + lrb[h];
            lre[(size_t)(bb * 8 + h) * L_TOK + t] = (1.0f / 64.0f) / (1.0f + expf(-v));
        }
    }
}

// ---------------- QKV GEMM: 128x64 tile, y = xn @ w.T, scatter to (B,NH,L,HD) ----------------
__global__ __launch_bounds__(256) void qkv_gemm_kernel(const float* __restrict__ A,
                                                       const float* __restrict__ qw,
                                                       const float* __restrict__ kw,
                                                       const float* __restrict__ vw,
                                                       float* __restrict__ XQ,
                                                       float* __restrict__ XK,
                                                       float* __restrict__ XV) {
    __shared__ float As[16][136];   // A-tile transposed: [k][row], stride 136
    __shared__ float Bs[16][68];
    int tid = threadIdx.x;
    int mt = blockIdx.x, nt = blockIdx.y;            // 128 x 24
    const float* wsel = (nt < 8) ? qw : (nt < 16) ? kw : vw;
    int h = nt & 7;
    int arow = tid >> 1, ak = (tid & 1) << 3;        // A: 128 rows x 16 k
    int brow = tid >> 2, bk = (tid & 3) << 2;        // B: 64 rows x 16 k
    int tm8 = (tid >> 4) << 3, tn = tid & 15;
    float acc[8][4] = {};
    const float* ap = A + (size_t)(mt * 128 + arow) * DIMC + ak;
    const float* bp = wsel + (size_t)(h * 64 + brow) * DIMC + bk;
    for (int k0 = 0; k0 < DIMC; k0 += 16) {
        float4 a0 = *(const float4*)(ap + k0);
        float4 a1 = *(const float4*)(ap + k0 + 4);
        float4 bv = *(const float4*)(bp + k0);
        As[ak + 0][arow] = a0.x; As[ak + 1][arow] = a0.y; As[ak + 2][arow] = a0.z; As[ak + 3][arow] = a0.w;
        As[ak + 4][arow] = a1.x; As[ak + 5][arow] = a1.y; As[ak + 6][arow] = a1.z; As[ak + 7][arow] = a1.w;
        Bs[bk + 0][brow] = bv.x; Bs[bk + 1][brow] = bv.y; Bs[bk + 2][brow] = bv.z; Bs[bk + 3][brow] = bv.w;
        __syncthreads();
#pragma unroll
        for (int kk = 0; kk < 16; kk++) {
            float4 va0 = *(const float4*)&As[kk][tm8];
            float4 va1 = *(const float4*)&As[kk][tm8 + 4];
            float4 vb  = *(const float4*)&Bs[kk][tn << 2];
            float aa[8] = {va0.x, va0.y, va0.z, va0.w, va1.x, va1.y, va1.z, va1.w};
            float bb[4] = {vb.x, vb.y, vb.z, vb.w};
#pragma unroll
            for (int i = 0; i < 8; i++)
#pragma unroll
                for (int j = 0; j < 4; j++)
                    acc[i][j] = fmaf(aa[i], bb[j], acc[i][j]);
        }
        __syncthreads();
    }
    int m0 = mt * 128 + tm8;                     // tile never straddles a batch (4096/128=32)
    int bb2 = m0 >> 12, t = m0 & 4095;
    float* dst = (nt < 8) ? XQ : (nt < 16) ? XK : XV;
    dst += ((size_t)(bb2 * 8 + h) * L_TOK + t) * 64 + (tn << 2);
#pragma unroll
    for (int i = 0; i < 8; i++)
        *(float4*)(dst + (size_t)i * 64) = make_float4(acc[i][0], acc[i][1], acc[i][2], acc[i][3]);
}

// ---------------- RoPE in-place on XQ and XK ----------------
__global__ __launch_bounds__(256) void rope_kernel(float* __restrict__ XQ, float* __restrict__ XK,
                                                   const float* __restrict__ ctab,
                                                   const float* __restrict__ stab) {
    int idx = blockIdx.x * 256 + threadIdx.x;   // 2 * 32 * 4096 * 32
    int d = idx & 31;
    int t = (idx >> 5) & 4095;
    int bh = (idx >> 17) & 31;
    int tensor = idx >> 22;
    float* p = (tensor ? XK : XQ) + ((size_t)bh * L_TOK + t) * 64;
    float c = ctab[(t << 5) + d], s = stab[(t << 5) + d];
    float x1 = p[d], x2 = p[d + 32];
    p[d] = x1 * c - x2 * s;
    p[d + 32] = x2 * c + x1 * s;
}

// ---------------- TTT scan: 32 blocks (b,h), 256 chunks each ----------------
// Round-9/13 verified version (measured twice: 1019/1022 us, VGPR 204, passing).
// 256 threads, single chain per block. CLOSED AXIS: any 512-thread/2-chain widening
// spills (~76 regs) under the backend's hard 128-VGPR cap for 512-thread workgroups;
// __launch_bounds__(512,2) and amdgpu_waves_per_eu(2,2) both failed to raise it
// (rounds 10/11/14: 4.27-4.28 ms). Do not revisit without a compiler upgrade.
__global__ __launch_bounds__(256) void scan_kernel(const float* __restrict__ XQ,
                                                   const float* __restrict__ XK,
                                                   const float* __restrict__ XV,
                                                   const float* __restrict__ lre,
                                                   const float* __restrict__ tok_delta,
                                                   const float* __restrict__ W1i,
                                                   const float* __restrict__ b1i,
                                                   const float* __restrict__ tw,
                                                   const float* __restrict__ tb,
                                                   float* __restrict__ attn_out) {
    __shared__ float W1[64][64];
    __shared__ float b1v[64];
    __shared__ float xqs[2][16][68], xks[2][16][68], xvs[2][16][68];
    __shared__ float grads[16][68];
    __shared__ float etas[2][16];
    __shared__ float coefC[16][17];
    __shared__ float sj[16];
    int tid = threadIdx.x;
    int r = tid >> 4, dq = tid & 15, d0 = dq << 2;
    int bh = blockIdx.x, h = bh & 7, b = bh >> 3;
#pragma unroll
    for (int i = 0; i < 4; i++) {
        int c = r + (i << 4);
        *(float4*)&W1[c][d0] = *(const float4*)&W1i[(size_t)h * 4096 + c * 64 + d0];
    }
    if (r == 0) *(float4*)&b1v[d0] = *(const float4*)&b1i[h * 64 + d0];
    float4 gw = *(const float4*)&tw[h * 64 + d0];
    float4 bw = *(const float4*)&tb[h * 64 + d0];
    float tok_r = fmaxf(1.0f / (float)(r + 1) + tok_delta[r], 0.0f);
    float tok15 = fmaxf(1.0f / 16.0f + tok_delta[15], 0.0f);
    const size_t base = (size_t)bh * L_TOK * 64;
    {   // prologue: chunk 0
        size_t off = base + (size_t)r * 64 + d0;
        *(float4*)&xqs[0][r][d0] = *(const float4*)(XQ + off);
        *(float4*)&xks[0][r][d0] = *(const float4*)(XK + off);
        *(float4*)&xvs[0][r][d0] = *(const float4*)(XV + off);
        if (tid < 16) etas[0][tid] = lre[(size_t)bh * L_TOK + tid];
    }
    __syncthreads();
    int cur = 0;
    for (int n = 0; n < 256; n++) {
        // prefetch next chunk into registers (overlaps compute)
        int np = (n < 255) ? n + 1 : 255;
        size_t poff = base + (size_t)np * 1024 + (size_t)r * 64 + d0;
        float4 pfq = *(const float4*)(XQ + poff);
        float4 pfk = *(const float4*)(XK + poff);
        float4 pfv = *(const float4*)(XV + poff);
        float pfe = 0.0f;
        if (tid < 16) pfe = lre[(size_t)bh * L_TOK + np * 16 + tid];

        // ---- Phase A: z = b1 + xk@W1 ; z2 = b1 + xq@W1 ; att = xq[r].xk[dq]
        float4 b1reg = *(float4*)&b1v[d0];
        float4 z  = b1reg;
        float4 z2 = b1reg;
        float att = 0.0f;
#pragma unroll
        for (int c4 = 0; c4 < 16; c4++) {
            int c = c4 << 2;
            float4 xkr = *(float4*)&xks[cur][r][c];
            float4 xqr = *(float4*)&xqs[cur][r][c];
            float4 xkq = *(float4*)&xks[cur][dq][c];
            float4 w0 = *(float4*)&W1[c + 0][d0];
            float4 w1 = *(float4*)&W1[c + 1][d0];
            float4 w2 = *(float4*)&W1[c + 2][d0];
            float4 w3 = *(float4*)&W1[c + 3][d0];
            att += xqr.x * xkq.x + xqr.y * xkq.y + xqr.z * xkq.z + xqr.w * xkq.w;
            z  = f4fma(xkr.x, w0, z);  z  = f4fma(xkr.y, w1, z);
            z  = f4fma(xkr.z, w2, z);  z  = f4fma(xkr.w, w3, z);
            z2 = f4fma(xqr.x, w0, z2); z2 = f4fma(xqr.y, w1, z2);
            z2 = f4fma(xqr.z, w2, z2); z2 = f4fma(xqr.w, w3, z2);
        }
        // ---- LN-L2 backward on z -> grad
        float s = z.x + z.y + z.z + z.w;
        s += __shfl_xor(s, 1); s += __shfl_xor(s, 2); s += __shfl_xor(s, 4); s += __shfl_xor(s, 8);
        float mu = s * (1.0f / 64.0f);
        float4 dz = make_float4(z.x - mu, z.y - mu, z.z - mu, z.w - mu);
        float q = dz.x * dz.x + dz.y * dz.y + dz.z * dz.z + dz.w * dz.w;
        q += __shfl_xor(q, 1); q += __shfl_xor(q, 2); q += __shfl_xor(q, 4); q += __shfl_xor(q, 8);
        float rstd = rsqrtf(q * (1.0f / 64.0f) + 1e-6f);
        float4 xh = make_float4(dz.x * rstd, dz.y * rstd, dz.z * rstd, dz.w * rstd);
        float4 xvv = *(float4*)&xvs[cur][r][d0];
        float4 xkk = *(float4*)&xks[cur][r][d0];
        float4 gxh;
        gxh.x = (fmaf(gw.x, xh.x, bw.x) - (xvv.x - xkk.x)) * gw.x;
        gxh.y = (fmaf(gw.y, xh.y, bw.y) - (xvv.y - xkk.y)) * gw.y;
        gxh.z = (fmaf(gw.z, xh.z, bw.z) - (xvv.z - xkk.z)) * gw.z;
        gxh.w = (fmaf(gw.w, xh.w, bw.w) - (xvv.w - xkk.w)) * gw.w;
        float s1 = gxh.x + gxh.y + gxh.z + gxh.w;
        s1 += __shfl_xor(s1, 1); s1 += __shfl_xor(s1, 2); s1 += __shfl_xor(s1, 4); s1 += __shfl_xor(s1, 8);
        float s2 = gxh.x * xh.x + gxh.y * xh.y + gxh.z * xh.z + gxh.w * xh.w;
        s2 += __shfl_xor(s2, 1); s2 += __shfl_xor(s2, 2); s2 += __shfl_xor(s2, 4); s2 += __shfl_xor(s2, 8);
        float cgr = rstd * (1.0f / 64.0f);
        float4 grad;
        grad.x = (64.0f * gxh.x - s1 - xh.x * s2) * cgr;
        grad.y = (64.0f * gxh.y - s1 - xh.y * s2) * cgr;
        grad.z = (64.0f * gxh.z - s1 - xh.z * s2) * cgr;
        grad.w = (64.0f * gxh.w - s1 - xh.w * s2) * cgr;
        *(float4*)&grads[r][d0] = grad;
        float ceta = etas[cur][dq];
        coefC[r][dq] = (dq <= r) ? tok_r * ceta * (1.0f + att) : 0.0f;
        if (r == 15) sj[dq] = tok15 * ceta;
        __syncthreads();   // sync1: grads/coefC/sj ready; all W1/b1 reads done

        // ---- Phase B: z2 -= C@grad ; W1/b1 update accumulators (rows 4r..4r+3)
        int r4 = r << 2;
        float4 acc0 = make_float4(0, 0, 0, 0), acc1 = acc0, acc2 = acc0, acc3 = acc0, accb = acc0;
#pragma unroll
        for (int j = 0; j < 16; j++) {
            float4 gj = *(float4*)&grads[j][d0];
            float cj = coefC[r][j];
            float sjj = sj[j];
            float4 xk4 = *(float4*)&xks[cur][j][r4];
            z2 = f4fma(-cj, gj, z2);
            acc0 = f4fma(sjj * xk4.x, gj, acc0);
            acc1 = f4fma(sjj * xk4.y, gj, acc1);
            acc2 = f4fma(sjj * xk4.z, gj, acc2);
            acc3 = f4fma(sjj * xk4.w, gj, acc3);
            accb = f4fma(sjj, gj, accb);
        }
        // ---- LN forward on z2 -> out = xq + LN(z2)
        float so = z2.x + z2.y + z2.z + z2.w;
        so += __shfl_xor(so, 1); so += __shfl_xor(so, 2); so += __shfl_xor(so, 4); so += __shfl_xor(so, 8);
        float mu2 = so * (1.0f / 64.0f);
        float4 dz2 = make_float4(z2.x - mu2, z2.y - mu2, z2.z - mu2, z2.w - mu2);
        float q2 = dz2.x * dz2.x + dz2.y * dz2.y + dz2.z * dz2.z + dz2.w * dz2.w;
        q2 += __shfl_xor(q2, 1); q2 += __shfl_xor(q2, 2); q2 += __shfl_xor(q2, 4); q2 += __shfl_xor(q2, 8);
        float rstd2 = rsqrtf(q2 * (1.0f / 64.0f) + 1e-6f);
        float4 xq4 = *(float4*)&xqs[cur][r][d0];
        float4 o;
        o.x = fmaf(dz2.x * rstd2, gw.x, bw.x) + xq4.x;
        o.y = fmaf(dz2.y * rstd2, gw.y, bw.y) + xq4.y;
        o.z = fmaf(dz2.z * rstd2, gw.z, bw.z) + xq4.z;
        o.w = fmaf(dz2.w * rstd2, gw.w, bw.w) + xq4.w;
        *(float4*)(attn_out + ((size_t)b * L_TOK + (size_t)n * 16 + r) * DIMC + h * 64 + d0) = o;

        // ---- W1 RMW (in-place, rows 4r..4r+3): no reader until after sync2
        {
            float4 w0 = *(float4*)&W1[r4 + 0][d0];
            *(float4*)&W1[r4 + 0][d0] = make_float4(w0.x - acc0.x, w0.y - acc0.y, w0.z - acc0.z, w0.w - acc0.w);
            float4 w1 = *(float4*)&W1[r4 + 1][d0];
            *(float4*)&W1[r4 + 1][d0] = make_float4(w1.x - acc1.x, w1.y - acc1.y, w1.z - acc1.z, w1.w - acc1.w);
            float4 w2 = *(float4*)&W1[r4 + 2][d0];
            *(float4*)&W1[r4 + 2][d0] = make_float4(w2.x - acc2.x, w2.y - acc2.y, w2.z - acc2.z, w2.w - acc2.w);
            float4 w3 = *(float4*)&W1[r4 + 3][d0];
            *(float4*)&W1[r4 + 3][d0] = make_float4(w3.x - acc3.x, w3.y - acc3.y, w3.z - acc3.z, w3.w - acc3.w);
        }
        if (r == 0)
            *(float4*)&b1v[d0] = make_float4(b1reg.x - accb.x, b1reg.y - accb.y, b1reg.z - accb.z, b1reg.w - accb.w);

        // ---- stage prefetched chunk into the other buffer
        int nxt = cur ^ 1;
        *(float4*)&xqs[nxt][r][d0] = pfq;
        *(float4*)&xks[nxt][r][d0] = pfk;
        *(float4*)&xvs[nxt][r][d0] = pfv;
        if (tid < 16) etas[nxt][tid] = pfe;
        __syncthreads();   // sync2: updated W1/b1 + staged inputs visible
        cur ^= 1;
    }
}

// ---------------- Post-LN (eps 1e-6) in-place on attn (B*L, 512) ----------------
__global__ __launch_bounds__(256) void post_ln_kernel(float* __restrict__ at,
                                                      const float* __restrict__ w,
                                                      const float* __restrict__ b) {
    __shared__ float redA[4], redB[4];
    int row = blockIdx.x, tid = threadIdx.x;
    float* p = at + (size_t)row * DIMC;
    float v0 = p[tid], v1 = p[tid + 256];
    float s = v0 + v1, q = v0 * v0 + v1 * v1;
    s += __shfl_xor(s, 1); s += __shfl_xor(s, 2); s += __shfl_xor(s, 4);
    s += __shfl_xor(s, 8); s += __shfl_xor(s, 16); s += __shfl_xor(s, 32);
    q += __shfl_xor(q, 1); q += __shfl_xor(q, 2); q += __shfl_xor(q, 4);
    q += __shfl_xor(q, 8); q += __shfl_xor(q, 16); q += __shfl_xor(q, 32);
    if ((tid & 63) == 0) { redA[tid >> 6] = s; redB[tid >> 6] = q; }
    __syncthreads();
    s = redA[0] + redA[1] + redA[2] + redA[3];
    q = redB[0] + redB[1] + redB[2] + redB[3];
    float mu = s * (1.0f / 512.0f);
    float rs = rsqrtf(q * (1.0f / 512.0f) - mu * mu + 1e-6f);
    p[tid]       = fmaf((v0 - mu) * rs, w[tid],       b[tid]);
    p[tid + 256] = fmaf((v1 - mu) * rs, w[tid + 256], b[tid + 256]);
}

// ---------------- Output GEMM: 128x64 tile, y = ln_out @ o_w.T, store transposed ----------------
__global__ __launch_bounds__(256) void out_gemm_kernel(const float* __restrict__ A,
                                                       const float* __restrict__ ow,
                                                       float* __restrict__ out) {
    __shared__ float As[16][136];
    __shared__ float Bs[16][68];
    int tid = threadIdx.x;
    int mt = blockIdx.x, nt = blockIdx.y;   // 128 x 8
    int arow = tid >> 1, ak = (tid & 1) << 3;
    int brow = tid >> 2, bk = (tid & 3) << 2;
    int tm8 = (tid >> 4) << 3, tn = tid & 15;
    float acc[8][4] = {};
    const float* ap = A + (size_t)(mt * 128 + arow) * DIMC + ak;
    const float* bp = ow + (size_t)(nt * 64 + brow) * DIMC + bk;
    for (int k0 = 0; k0 < DIMC; k0 += 16) {
        float4 a0 = *(const float4*)(ap + k0);
        float4 a1 = *(const float4*)(ap + k0 + 4);
        float4 bv = *(const float4*)(bp + k0);
        As[ak + 0][arow] = a0.x; As[ak + 1][arow] = a0.y; As[ak + 2][arow] = a0.z; As[ak + 3][arow] = a0.w;
        As[ak + 4][arow] = a1.x; As[ak + 5][arow] = a1.y; As[ak + 6][arow] = a1.z; As[ak + 7][arow] = a1.w;
        Bs[bk + 0][brow] = bv.x; Bs[bk + 1][brow] = bv.y; Bs[bk + 2][brow] = bv.z; Bs[bk + 3][brow] = bv.w;
        __syncthreads();
#pragma unroll
        for (int kk = 0; kk < 16; kk++) {
            float4 va0 = *(const float4*)&As[kk][tm8];
            float4 va1 = *(const float4*)&As[kk][tm8 + 4];
            float4 vb  = *(const float4*)&Bs[kk][tn << 2];
            float aa[8] = {va0.x, va0.y, va0.z, va0.w, va1.x, va1.y, va1.z, va1.w};
            float bb[4] = {vb.x, vb.y, vb.z, vb.w};
#pragma unroll
            for (int i = 0; i < 8; i++)
#pragma unroll
                for (int j = 0; j < 4; j++)
                    acc[i][j] = fmaf(aa[i], bb[j], acc[i][j]);
        }
        __syncthreads();
    }
    int m0 = mt * 128 + tm8;                 // tile never straddles a batch
    int bb2 = m0 >> 12, t = m0 & 4095;
    int n0 = nt * 64 + (tn << 2);
#pragma unroll
    for (int j = 0; j < 4; j++) {
        float* op = out + ((size_t)(bb2 * DIMC) + n0 + j) * L_TOK + t;
        *(float4*)op       = make_float4(acc[0][j], acc[1][j], acc[2][j], acc[3][j]);
        *(float4*)(op + 4) = make_float4(acc[4][j], acc[5][j], acc[6][j], acc[7][j]);
    }
}

// ---------------- launch ----------------
extern "C" void kernel_launch(void* const* d_in, const int* in_sizes, int n_in,
                              void* d_out, int out_size, void* d_ws, size_t ws_size,
                              hipStream_t stream) {
    (void)in_sizes; (void)n_in; (void)out_size; (void)ws_size;
    const float* x       = (const float*)d_in[0];
    const float* ln_w    = (const float*)d_in[1];
    const float* ln_b    = (const float*)d_in[2];
    const float* q_w     = (const float*)d_in[3];
    const float* k_w     = (const float*)d_in[4];
    const float* v_w     = (const float*)d_in[5];
    const float* o_w     = (const float*)d_in[6];
    const float* W1      = (const float*)d_in[7];
    const float* b1      = (const float*)d_in[8];
    const float* ttt_w   = (const float*)d_in[9];
    const float* ttt_b   = (const float*)d_in[10];
    const float* lr_w    = (const float*)d_in[11];
    const float* lr_b    = (const float*)d_in[12];
    const float* tok_d   = (const float*)d_in[13];
    const float* post_w  = (const float*)d_in[14];
    const float* post_b  = (const float*)d_in[15];

    float* ws = (float*)d_ws;
    const size_t NTD = (size_t)4 * L_TOK * DIMC;   // 8388608 floats = 32 MB
    // Workspace layout (~102 MB): xn | XQ | XK | lre | ctab | stab.
    // XV lives in d_out; it is fully consumed by scan_kernel before
    // out_gemm_kernel overwrites d_out with the final result.
    float* xn   = ws;
    float* XQb  = ws + NTD;
    float* XKb  = ws + 2 * NTD;
    float* XVb  = (float*)d_out;
    float* lre  = ws + 3 * NTD;
    float* ctab = lre + 131072;
    float* stab = ctab + 131072;
    float* attn = xn;

    rope_table_kernel<<<512, 256, 0, stream>>>(ctab, stab);
    ln_in_kernel<<<1024, 256, 0, stream>>>(x, ln_w, ln_b, xn);
    lr_kernel<<<4096, 256, 0, stream>>>(xn, lr_w, lr_b, lre);
    {
        dim3 g(128, 24);
        qkv_gemm_kernel<<<g, 256, 0, stream>>>(xn, q_w, k_w, v_w, XQb, XKb, XVb);
    }
    rope_kernel<<<32768, 256, 0, stream>>>(XQb, XKb, ctab, stab);
    scan_kernel<<<32, 256, 0, stream>>>(XQb, XKb, XVb, lre, tok_d, W1, b1, ttt_w, ttt_b, attn);
    post_ln_kernel<<<16384, 256, 0, stream>>>(attn, post_w, post_b);
    {
        dim3 g(128, 8);
        out_gemm_kernel<<<g, 256, 0, stream>>>(attn, o_w, (float*)d_out);
    }
}